// Round 2
// baseline (3502.210 us; speedup 1.0000x reference)
//
#include <hip/hip_runtime.h>
#include <math.h>

// Problem constants
constexpr int N_ = 32, C_ = 512, T_ = 1024;
constexpr int NTOK = N_ * T_;      // 32768 tokens
constexpr int NCODE = 2048;
constexpr int K = 512;

#define MUF 0.99f
#define OMM 0.01f                  // f32(1.0 - 0.99)

// Output layout (flat f32, return order)
constexpr long long OFF_XD   = 0;                                  // (32,512,1024)
constexpr long long OFF_LOSS = 16777216;                           // scalar
constexpr long long OFF_PERP = 16777217;                           // scalar
constexpr long long OFF_CB   = 16777218;                           // new_codebook (2048,512)
constexpr long long OFF_CSUM = OFF_CB  + (long long)NCODE * C_;    // code_sum_ema
constexpr long long OFF_CCNT = OFF_CSUM + (long long)NCODE * C_;   // code_count_ema
// NOTE: d_ws is NOT used at all. Scratch (code_idx ints, raw counts, loss acc)
// lives inside d_out regions that are finalized by later kernels:
//   - code_idx (int) in out[OFF_CB .. OFF_CB+32768)  -> overwritten by k_update_cb
//   - raw counts in out[OFF_CCNT]                    -> EMA'd in-place by k_ccnt (last)
//   - loss accumulator in out[OFF_LOSS]              -> divided in-place by k_scalars

// ---------------------------------------------------------------- argmin (runs FIRST; reads only inputs)
// 16 tokens/block, full K resident in LDS (32 KB); stream 2048 codes in tiles of 256.
// Code norms accumulated inline (no cross-kernel norm state).
#define KCH 16
#define NCT 256
__global__ __launch_bounds__(256)
void k_argmin(const float* __restrict__ x, const float* __restrict__ cb,
              int* __restrict__ code_idx) {
    __shared__ float xs[K][16];        // [k][tok]   32768 B
    __shared__ float cs[KCH][NCT];     // [k][code]  16384 B
    const int tid = threadIdx.x;
    const int g = blockIdx.x;          // token group: n = g>>6, t0 = (g&63)*16
    const int n = g >> 6;
    const int t0 = (g & 63) * 16;
    const long long xbase = (long long)n * C_ * T_ + t0;

    // Stage x tile: 16 tokens x 512 coords = 2048 float4
    #pragma unroll
    for (int it = 0; it < 8; ++it) {
        int u = tid + it * 256;        // 0..2047
        int c = u >> 2, r = u & 3;
        float4 v = *(const float4*)(x + xbase + (long long)c * T_ + r * 4);
        *(float4*)&xs[c][r * 4] = v;
    }

    const int wv = tid >> 6;           // wave id 0..3 -> tokens wv*4..+3
    const int cg = tid & 63;           // lane -> codes cg*4..+3 within tile
    float bd[4]; int bj[4];
    #pragma unroll
    for (int t = 0; t < 4; ++t) { bd[t] = 3.4e38f; bj[t] = 0; }

    for (int jt = 0; jt < NCODE; jt += NCT) {
        float acc[4][4];
        float nq[4];
        #pragma unroll
        for (int t = 0; t < 4; ++t) { nq[t] = 0.0f;
            #pragma unroll
            for (int q = 0; q < 4; ++q) acc[t][q] = 0.0f; }

        for (int kc = 0; kc < K; kc += KCH) {
            __syncthreads();           // also covers initial xs staging
            // stage cs: 256 codes x 16 k, transposed to [k][code]
            #pragma unroll
            for (int s = 0; s < 4; ++s) {
                int u = tid + s * 256;             // 0..1023
                int j = u >> 2, q = u & 3;
                float4 v = *(const float4*)(cb + (long long)(jt + j) * K + kc + q * 4);
                cs[q * 4 + 0][j] = v.x;
                cs[q * 4 + 1][j] = v.y;
                cs[q * 4 + 2][j] = v.z;
                cs[q * 4 + 3][j] = v.w;
            }
            __syncthreads();
            #pragma unroll
            for (int kk = 0; kk < KCH; ++kk) {
                float4 xv = *(const float4*)&xs[kc + kk][wv * 4];  // broadcast across wave
                float4 cv = *(const float4*)&cs[kk][cg * 4];       // conflict-free b128
                float xa[4] = {xv.x, xv.y, xv.z, xv.w};
                float ca[4] = {cv.x, cv.y, cv.z, cv.w};
                #pragma unroll
                for (int q = 0; q < 4; ++q) {
                    nq[q] += ca[q] * ca[q];
                    #pragma unroll
                    for (int t = 0; t < 4; ++t) acc[t][q] += xa[t] * ca[q];
                }
            }
        }
        // fold into running argmin (ascending j => strict < keeps first-min)
        #pragma unroll
        for (int q = 0; q < 4; ++q) {
            int j = jt + cg * 4 + q;
            #pragma unroll
            for (int t = 0; t < 4; ++t) {
                float d = nq[q] - 2.0f * acc[t][q];
                if (d < bd[t]) { bd[t] = d; bj[t] = j; }
            }
        }
    }

    // full 64-lane lexicographic (d, j) min
    #pragma unroll
    for (int off = 1; off < 64; off <<= 1) {
        #pragma unroll
        for (int t = 0; t < 4; ++t) {
            float od = __shfl_xor(bd[t], off, 64);
            int   oj = __shfl_xor(bj[t], off, 64);
            if (od < bd[t] || (od == bd[t] && oj < bj[t])) { bd[t] = od; bj[t] = oj; }
        }
    }
    if (cg == 0) {
        #pragma unroll
        for (int t = 0; t < 4; ++t)
            code_idx[g * 16 + wv * 4 + t] = bj[t];
    }
}

// ---------------------------------------------------------------- init (zeros + EMA base)
__global__ void k_init(const float* __restrict__ code_sum, float* __restrict__ out) {
    int i = blockIdx.x * 256 + threadIdx.x;
    if (i < NCODE * C_) out[OFF_CSUM + i] = MUF * code_sum[i];
    if (i < NCODE)      out[OFF_CCNT + i] = 0.0f;
    if (i == 0)         out[OFF_LOSS] = 0.0f;
}

// ---------------------------------------------------------------- fused x_d_out + loss + scatter
__global__ void k_scatter(const float* __restrict__ x, const float* __restrict__ cb,
                          float* __restrict__ out) {
    const int* code_idx = (const int*)(out + OFF_CB);
    const int t = blockIdx.x * 256 + threadIdx.x;   // gridDim.x = 4
    const int cblk = blockIdx.y;                    // 0..7
    const int n = blockIdx.z;                       // 0..31
    const int tok = n * T_ + t;
    const int idx = code_idx[tok];
    if (cblk == 0) atomicAdd(&out[OFF_CCNT + idx], 1.0f);

    const float* cbrow = cb + (long long)idx * C_;
    float* csum = out + OFF_CSUM + (long long)idx * C_;
    const long long base = (long long)n * C_ * T_ + t;
    float lsum = 0.0f;
    const int c0 = cblk * 64;
    for (int c = c0; c < c0 + 64; ++c) {
        float xv = x[base + (long long)c * T_];
        float cv = cbrow[c];
        float dv = cv - xv;
        out[OFF_XD + base + (long long)c * T_] = xv + dv;
        lsum += dv * dv;
        atomicAdd(csum + c, OMM * xv);
    }
    #pragma unroll
    for (int off = 32; off >= 1; off >>= 1) lsum += __shfl_down(lsum, off, 64);
    __shared__ float red[4];
    if ((threadIdx.x & 63) == 0) red[threadIdx.x >> 6] = lsum;
    __syncthreads();
    if (threadIdx.x == 0)
        atomicAdd(&out[OFF_LOSS], red[0] + red[1] + red[2] + red[3]);
}

// ---------------------------------------------------------------- scalars (reads RAW counts; before k_ccnt)
__global__ void k_scalars(float* __restrict__ out) {
    __shared__ float sred[256];
    int tid = threadIdx.x;
    float s = 0.0f;
    for (int j = tid; j < NCODE; j += 256) s += out[OFF_CCNT + j];
    sred[tid] = s; __syncthreads();
    for (int st = 128; st > 0; st >>= 1) { if (tid < st) sred[tid] += sred[tid + st]; __syncthreads(); }
    float total = sred[0];
    __syncthreads();
    float inv = 1.0f / (total + 1e-10f);
    float h = 0.0f;
    for (int j = tid; j < NCODE; j += 256) {
        float p = out[OFF_CCNT + j] * inv;
        h += p * logf(p + 1e-7f);
    }
    sred[tid] = h; __syncthreads();
    for (int st = 128; st > 0; st >>= 1) { if (tid < st) sred[tid] += sred[tid + st]; __syncthreads(); }
    if (tid == 0) {
        out[OFF_PERP] = expf(-sred[0]);
        out[OFF_LOSS] = out[OFF_LOSS] / 16777216.0f;   // mean over (N*T, C)
    }
}

// ---------------------------------------------------------------- codebook update/reset (reads RAW counts; overwrites idx)
__global__ void k_update_cb(const float* __restrict__ x, const float* __restrict__ code_count,
                            float* __restrict__ out) {
    int e = blockIdx.x * 256 + threadIdx.x;   // < NCODE*C_
    int j = e >> 9, c = e & 511;
    float nc = out[OFF_CCNT + j];
    float cema = MUF * code_count[j] + OMM * nc;
    float se = out[OFF_CSUM + e];
    float val;
    if (cema >= 1.0f) {
        val = se / fmaxf(cema, 1e-10f);
    } else {
        // reset to x_flat[j][c] = x[j/1024, c, j%1024]
        val = x[(long long)(j >> 10) * C_ * T_ + (long long)c * T_ + (j & 1023)];
    }
    out[OFF_CB + e] = val;
}

// ---------------------------------------------------------------- count EMA in-place (LAST)
__global__ void k_ccnt(const float* __restrict__ code_count, float* __restrict__ out) {
    int j = blockIdx.x * 256 + threadIdx.x;
    if (j < NCODE) {
        float nc = out[OFF_CCNT + j];
        out[OFF_CCNT + j] = MUF * code_count[j] + OMM * nc;
    }
}

// ---------------------------------------------------------------- launch
extern "C" void kernel_launch(void* const* d_in, const int* in_sizes, int n_in,
                              void* d_out, int out_size, void* d_ws, size_t ws_size,
                              hipStream_t stream) {
    const float* x          = (const float*)d_in[0];
    const float* codebook   = (const float*)d_in[1];
    const float* code_sum   = (const float*)d_in[2];
    const float* code_count = (const float*)d_in[3];
    float* out = (float*)d_out;
    int* code_idx = (int*)(out + OFF_CB);     // transient; overwritten by k_update_cb

    k_argmin   <<<NTOK / 16, 256, 0, stream>>>(x, codebook, code_idx);
    k_init     <<<(NCODE * C_ + 255) / 256, 256, 0, stream>>>(code_sum, out);
    dim3 g2(4, 8, 32);
    k_scatter  <<<g2, 256, 0, stream>>>(x, codebook, out);
    k_scalars  <<<1, 256, 0, stream>>>(out);
    k_update_cb<<<(NCODE * C_ + 255) / 256, 256, 0, stream>>>(x, code_count, out);
    k_ccnt     <<<(NCODE + 255) / 256, 256, 0, stream>>>(code_count, out);
}

// Round 3
// 1771.030 us; speedup vs baseline: 1.9775x; 1.9775x over previous
//
#include <hip/hip_runtime.h>
#include <math.h>

constexpr int N_ = 32, C_ = 512, T_ = 1024;
constexpr int NTOK = N_ * T_;      // 32768
constexpr int NCODE = 2048;
constexpr int K = 512;

#define MUF 0.99f
#define OMM 0.01f

// Output layout (flat f32, return order)
constexpr long long OFF_XD   = 0;
constexpr long long OFF_LOSS = 16777216;
constexpr long long OFF_PERP = 16777217;
constexpr long long OFF_CB   = 16777218;                           // new_codebook (2048,512)
constexpr long long OFF_CSUM = OFF_CB  + (long long)NCODE * C_;
constexpr long long OFF_CCNT = OFF_CSUM + (long long)NCODE * C_;
// Scratch lives inside the CB region (1,048,576 elems), overwritten last by k_update_cb.
constexpr long long S_IDX  = OFF_CB;             // int[32768]
constexpr long long S_NRM  = OFF_CB + 32768;     // float[2048]  half-norms
constexpr long long S_CNT  = OFF_CB + 34816;     // int[2048]
constexpr long long S_BASE = OFF_CB + 36864;     // int[2048]
constexpr long long S_CUR  = OFF_CB + 38912;     // int[2048]
constexpr long long S_TOK  = OFF_CB + 40960;     // int[32768]
constexpr long long S_PBD  = OFF_CB + 73728;     // float[2][32768]
constexpr long long S_PBJ  = OFF_CB + 139264;    // int[2][32768]

// -------------------------------------------------- norms (+ zero init)
__global__ void k_norm(const float* __restrict__ cb, float* __restrict__ out) {
    int j = blockIdx.x, l = threadIdx.x;      // 2048 x 64
    const float* row = cb + (long long)j * K;
    float4 a = *(const float4*)(row + l * 8);
    float4 b = *(const float4*)(row + l * 8 + 4);
    float s = a.x*a.x + a.y*a.y + a.z*a.z + a.w*a.w
            + b.x*b.x + b.y*b.y + b.z*b.z + b.w*b.w;
    #pragma unroll
    for (int off = 32; off >= 1; off >>= 1) s += __shfl_down(s, off, 64);
    if (l == 0) out[S_NRM + j] = 0.5f * s;    // half-norm: argmin(||c||^2/2 - x.c)
    if (l == 1) ((int*)(out + S_CNT))[j] = 0;
    if (j == 0 && l == 2) out[OFF_LOSS] = 0.0f;
}

// -------------------------------------------------- argmin: 64 tok x 1024 codes per block
// grid (512, 2): y = code-half. 256 thr: tg=tid>>5 (8 groups x 8 tok), cg=tid&31 (codes cg*4 & 128+cg*4)
#define KCH 16
__global__ __launch_bounds__(256)
void k_argmin(const float* __restrict__ x, const float* __restrict__ cb,
              const float* __restrict__ nrm, float* __restrict__ pbd,
              int* __restrict__ pbj) {
    __shared__ float xs[KCH][64];
    __shared__ float cs[KCH][256];
    const int tid = threadIdx.x;
    const int g = blockIdx.x;                  // n = g>>4, t0=(g&15)*64; tokens [g*64, g*64+64)
    const int zb = blockIdx.y * 1024;          // code half
    const long long xb = (long long)(g >> 4) * C_ * T_ + (g & 15) * 64;
    const int tg = tid >> 5, cg = tid & 31;

    float bd[8]; int bj[8];
    #pragma unroll
    for (int t = 0; t < 8; ++t) { bd[t] = 3.4e38f; bj[t] = 0; }

    for (int jt = zb; jt < zb + 1024; jt += 256) {
        float acc[8][8];
        #pragma unroll
        for (int t = 0; t < 8; ++t)
            #pragma unroll
            for (int q = 0; q < 8; ++q) acc[t][q] = 0.0f;

        for (int kc = 0; kc < K; kc += KCH) {
            __syncthreads();
            { // xs: 16 rows x 64 tok
                int r = tid >> 4, cc = (tid & 15) * 4;
                float4 v = *(const float4*)(x + xb + (long long)(kc + r) * T_ + cc);
                *(float4*)&xs[r][cc] = v;
            }
            #pragma unroll
            for (int s = 0; s < 4; ++s) { // cs transpose: 256 codes x 16 k
                int u = tid + 256 * s;
                int j = u >> 2, q = u & 3;
                float4 v = *(const float4*)(cb + (long long)(jt + j) * K + kc + q * 4);
                cs[q * 4 + 0][j] = v.x;
                cs[q * 4 + 1][j] = v.y;
                cs[q * 4 + 2][j] = v.z;
                cs[q * 4 + 3][j] = v.w;
            }
            __syncthreads();
            #pragma unroll
            for (int kk = 0; kk < KCH; ++kk) {
                float4 xa = *(const float4*)&xs[kk][tg * 8];
                float4 xb4= *(const float4*)&xs[kk][tg * 8 + 4];
                float4 ca = *(const float4*)&cs[kk][cg * 4];
                float4 cb4= *(const float4*)&cs[kk][128 + cg * 4];
                float xv[8] = {xa.x, xa.y, xa.z, xa.w, xb4.x, xb4.y, xb4.z, xb4.w};
                float cv[8] = {ca.x, ca.y, ca.z, ca.w, cb4.x, cb4.y, cb4.z, cb4.w};
                #pragma unroll
                for (int t = 0; t < 8; ++t)
                    #pragma unroll
                    for (int q = 0; q < 8; ++q) acc[t][q] += xv[t] * cv[q];
            }
        }
        // fold: ascending j within thread (q 0..3 then +128 group)
        #pragma unroll
        for (int q = 0; q < 8; ++q) {
            int j = jt + ((q >> 2) * 128) + cg * 4 + (q & 3);
            float h = nrm[j];
            #pragma unroll
            for (int t = 0; t < 8; ++t) {
                float d = h - acc[t][q];
                if (d < bd[t]) { bd[t] = d; bj[t] = j; }
            }
        }
    }
    // reduce across 32 cg lanes (xor<=16 stays in half-wave)
    #pragma unroll
    for (int off = 16; off >= 1; off >>= 1) {
        #pragma unroll
        for (int t = 0; t < 8; ++t) {
            float od = __shfl_xor(bd[t], off, 64);
            int   oj = __shfl_xor(bj[t], off, 64);
            if (od < bd[t] || (od == bd[t] && oj < bj[t])) { bd[t] = od; bj[t] = oj; }
        }
    }
    if ((tid & 31) == 0) {
        int base = blockIdx.y * NTOK + g * 64 + tg * 8;
        #pragma unroll
        for (int t = 0; t < 8; ++t) { pbd[base + t] = bd[t]; pbj[base + t] = bj[t]; }
    }
}

__global__ void k_merge(const float* __restrict__ pbd, const int* __restrict__ pbj,
                        int* __restrict__ idx) {
    int t = blockIdx.x * 256 + threadIdx.x;
    float d0 = pbd[t], d1 = pbd[NTOK + t];
    int j0 = pbj[t], j1 = pbj[NTOK + t];
    idx[t] = (d1 < d0) ? j1 : j0;             // tie -> lower j (half 0)
}

// -------------------------------------------------- counting sort
__global__ void k_hist(const int* __restrict__ idx, int* __restrict__ cnt) {
    int t = blockIdx.x * 256 + threadIdx.x;
    atomicAdd(&cnt[idx[t]], 1);
}

__global__ void k_scan(const int* __restrict__ cnt, int* __restrict__ base,
                       int* __restrict__ cursor, const float* __restrict__ code_count,
                       float* __restrict__ out) {
    __shared__ int ps[256];
    __shared__ float hs[256];
    int tid = threadIdx.x;
    int local[8]; int s = 0;
    #pragma unroll
    for (int q = 0; q < 8; ++q) { local[q] = cnt[tid * 8 + q]; s += local[q]; }
    ps[tid] = s; __syncthreads();
    for (int st = 1; st < 256; st <<= 1) {
        int v = (tid >= st) ? ps[tid - st] : 0;
        __syncthreads();
        ps[tid] += v;
        __syncthreads();
    }
    int b = ps[tid] - s;                      // exclusive base of this thread's chunk
    float h = 0.0f;
    #pragma unroll
    for (int q = 0; q < 8; ++q) {
        int j = tid * 8 + q;
        base[j] = b; cursor[j] = b; b += local[q];
        float p = (float)local[q] * (1.0f / 32768.0f);
        h += p * logf(p + 1e-7f);
        out[OFF_CCNT + j] = MUF * code_count[j] + OMM * (float)local[q];
    }
    hs[tid] = h; __syncthreads();
    for (int st = 128; st > 0; st >>= 1) {
        if (tid < st) hs[tid] += hs[tid + st];
        __syncthreads();
    }
    if (tid == 0) out[OFF_PERP] = expf(-hs[0]);
}

__global__ void k_place(const int* __restrict__ idx, int* __restrict__ cursor,
                        int* __restrict__ toklist) {
    int t = blockIdx.x * 256 + threadIdx.x;
    int pos = atomicAdd(&cursor[idx[t]], 1);
    toklist[pos] = t;
}

// -------------------------------------------------- code-side gather: code_sum_ema rows
__global__ void k_codesum(const float* __restrict__ x, const float* __restrict__ code_sum,
                          const int* __restrict__ cnt, const int* __restrict__ base,
                          const int* __restrict__ toklist, float* __restrict__ out) {
    int j = blockIdx.x, l = threadIdx.x;      // 2048 x 64
    float acc[8];
    #pragma unroll
    for (int q = 0; q < 8; ++q) acc[q] = 0.0f;
    int b = base[j], e = b + cnt[j];
    for (int i = b; i < e; ++i) {
        int tok = toklist[i];
        const float* xp = x + (long long)(tok >> 10) * C_ * T_ + (tok & 1023);
        #pragma unroll
        for (int q = 0; q < 8; ++q) acc[q] += xp[(long long)(q * 64 + l) * T_];
    }
    #pragma unroll
    for (int q = 0; q < 8; ++q) {
        long long o = (long long)j * C_ + q * 64 + l;
        out[OFF_CSUM + o] = MUF * code_sum[o] + OMM * acc[q];
    }
}

// -------------------------------------------------- x_d_out + commit loss (atomic-free scatter)
__global__ void k_xd(const float* __restrict__ x, const float* __restrict__ cb,
                     const int* __restrict__ idx, float* __restrict__ out) {
    const int t = blockIdx.x * 256 + threadIdx.x;  // grid (4,4,32)
    const int c0 = blockIdx.y * 128;
    const int n = blockIdx.z;
    const int j = idx[n * T_ + t];
    const float* cr = cb + (long long)j * C_ + c0;
    const long long base = (long long)n * C_ * T_ + t;
    float ls = 0.0f;
    for (int ci = 0; ci < 128; ++ci) {
        float xv = x[base + (long long)(c0 + ci) * T_];
        float dv = cr[ci] - xv;
        out[OFF_XD + base + (long long)(c0 + ci) * T_] = xv + dv;  // matches x + (x_d - x)
        ls += dv * dv;
    }
    #pragma unroll
    for (int off = 32; off >= 1; off >>= 1) ls += __shfl_down(ls, off, 64);
    __shared__ float red[4];
    if ((threadIdx.x & 63) == 0) red[threadIdx.x >> 6] = ls;
    __syncthreads();
    if (threadIdx.x == 0) atomicAdd(&out[OFF_LOSS], red[0] + red[1] + red[2] + red[3]);
}

// -------------------------------------------------- codebook update/reset (overwrites scratch) + loss scale
__global__ void k_update_cb(const float* __restrict__ x, float* __restrict__ out) {
    int e = blockIdx.x * 256 + threadIdx.x;   // 4096 blocks
    int j = e >> 9, c = e & 511;
    float cema = out[OFF_CCNT + j];
    float se = out[OFF_CSUM + e];
    float val;
    if (cema >= 1.0f) val = se / fmaxf(cema, 1e-10f);
    else val = x[(long long)(j >> 10) * C_ * T_ + (long long)c * T_ + (j & 1023)];
    out[OFF_CB + e] = val;
    if (e == 0) out[OFF_LOSS] *= (1.0f / 16777216.0f);   // exact pow2 scale == /2^24
}

// -------------------------------------------------- launch
extern "C" void kernel_launch(void* const* d_in, const int* in_sizes, int n_in,
                              void* d_out, int out_size, void* d_ws, size_t ws_size,
                              hipStream_t stream) {
    const float* x          = (const float*)d_in[0];
    const float* codebook   = (const float*)d_in[1];
    const float* code_sum   = (const float*)d_in[2];
    const float* code_count = (const float*)d_in[3];
    float* out = (float*)d_out;
    int*   idx     = (int*)(out + S_IDX);
    float* nrm     = out + S_NRM;
    int*   cnt     = (int*)(out + S_CNT);
    int*   base    = (int*)(out + S_BASE);
    int*   cursor  = (int*)(out + S_CUR);
    int*   toklist = (int*)(out + S_TOK);
    float* pbd     = out + S_PBD;
    int*   pbj     = (int*)(out + S_PBJ);

    k_norm     <<<NCODE, 64, 0, stream>>>(codebook, out);
    dim3 ga(512, 2);
    k_argmin   <<<ga, 256, 0, stream>>>(x, codebook, nrm, pbd, pbj);
    k_merge    <<<128, 256, 0, stream>>>(pbd, pbj, idx);
    k_hist     <<<128, 256, 0, stream>>>(idx, cnt);
    k_scan     <<<1, 256, 0, stream>>>(cnt, base, cursor, code_count, out);
    k_place    <<<128, 256, 0, stream>>>(idx, cursor, toklist);
    k_codesum  <<<NCODE, 64, 0, stream>>>(x, code_sum, cnt, base, toklist, out);
    dim3 gx(4, 4, 32);
    k_xd       <<<gx, 256, 0, stream>>>(x, codebook, idx, out);
    k_update_cb<<<4096, 256, 0, stream>>>(x, out);
}

// Round 4
// 766.292 us; speedup vs baseline: 4.5703x; 2.3112x over previous
//
#include <hip/hip_runtime.h>
#include <math.h>

constexpr int N_ = 32, C_ = 512, T_ = 1024;
constexpr int NTOK = N_ * T_;      // 32768
constexpr int NCODE = 2048;
constexpr int K = 512;

#define MUF 0.99f
#define OMM 0.01f

// Output layout (flat f32, return order)
constexpr long long OFF_XD   = 0;
constexpr long long OFF_LOSS = 16777216;
constexpr long long OFF_PERP = 16777217;
constexpr long long OFF_CB   = 16777218;                           // new_codebook (2048,512)
constexpr long long OFF_CSUM = OFF_CB  + (long long)NCODE * C_;
constexpr long long OFF_CCNT = OFF_CSUM + (long long)NCODE * C_;

// CB-region scratch (floats from OFF_CB; overwritten by k_update_cb last)
constexpr long long S_IDX  = OFF_CB;             // int[32768]
constexpr long long S_NRM  = OFF_CB + 32768;     // float[2048] half-norms
constexpr long long S_CNT  = OFF_CB + 34816;     // int[2048]
constexpr long long S_BASE = OFF_CB + 36864;     // int[2048]
constexpr long long S_CUR  = OFF_CB + 38912;     // int[2048]
constexpr long long S_TOK  = OFF_CB + 40960;     // int[32768]
constexpr long long S_PBD  = OFF_CB + 73728;     // float[8][32768]
constexpr long long S_PBJ  = OFF_CB + 335872;    // int[8][32768]
// CSUM region scratch: c_hi ushort[1M] then c_lo ushort[1M] (overwritten by k_codesum)
// XD region scratch: x_hi ushort[16.7M] then x_lo ushort[16.7M] (overwritten by k_xd)

typedef __bf16 bf16x8 __attribute__((ext_vector_type(8)));
typedef float f32x4 __attribute__((ext_vector_type(4)));

__device__ inline unsigned short f2bf(float f) {
    unsigned int u = __float_as_uint(f);
    unsigned int r = u + 0x7fffu + ((u >> 16) & 1u);
    return (unsigned short)(r >> 16);
}
__device__ inline float bf2f(unsigned short h) {
    return __uint_as_float(((unsigned int)h) << 16);
}

// ---------------------------------------------- prep: cb -> c_hi/c_lo + half-norms + zeros
__global__ void k_prep_cb(const float* __restrict__ cb, float* __restrict__ out) {
    int j = blockIdx.x, l = threadIdx.x;          // 2048 x 64
    unsigned short* chi = (unsigned short*)(out + OFF_CSUM);
    unsigned short* clo = chi + (long long)NCODE * K;
    const float* row = cb + (long long)j * K;
    float4 a = *(const float4*)(row + l * 8);
    float4 b = *(const float4*)(row + l * 8 + 4);
    float v[8] = {a.x, a.y, a.z, a.w, b.x, b.y, b.z, b.w};
    unsigned short h[8], lo[8];
    float s = 0.0f;
    #pragma unroll
    for (int k = 0; k < 8; ++k) {
        s += v[k] * v[k];
        h[k] = f2bf(v[k]);
        lo[k] = f2bf(v[k] - bf2f(h[k]));
    }
    *(uint4*)&chi[(long long)j * K + l * 8] = *(uint4*)h;
    *(uint4*)&clo[(long long)j * K + l * 8] = *(uint4*)lo;
    #pragma unroll
    for (int off = 32; off >= 1; off >>= 1) s += __shfl_down(s, off, 64);
    if (l == 0) out[S_NRM + j] = 0.5f * s;
    if (l == 1) ((int*)(out + S_CNT))[j] = 0;
    if (j == 0 && l == 2) out[OFF_LOSS] = 0.0f;
}

// ---------------------------------------------- transpose x -> token-major bf16 hi/lo
__global__ void k_transpose(const float* __restrict__ x, float* __restrict__ out) {
    __shared__ unsigned int tile[64][65];
    unsigned short* xhi = (unsigned short*)(out + OFF_XD);
    unsigned short* xlo = xhi + (long long)NTOK * C_;
    const int t0 = blockIdx.x * 64, c0 = blockIdx.y * 64, n = blockIdx.z;
    const int tid = threadIdx.x;
    #pragma unroll
    for (int i = 0; i < 4; ++i) {
        int s = tid + 256 * i;
        int cl = s >> 4, tq = (s & 15) * 4;
        float4 v = *(const float4*)(x + ((long long)(n * C_ + c0 + cl)) * T_ + t0 + tq);
        float vv[4] = {v.x, v.y, v.z, v.w};
        #pragma unroll
        for (int k = 0; k < 4; ++k) {
            unsigned short h = f2bf(vv[k]);
            unsigned short lo = f2bf(vv[k] - bf2f(h));
            tile[cl][tq + k] = ((unsigned int)h << 16) | lo;
        }
    }
    __syncthreads();
    #pragma unroll
    for (int i = 0; i < 4; ++i) {
        int s = tid + 256 * i;
        int tr = s >> 4, cq = (s & 15) * 4;
        unsigned short h4[4], l4[4];
        #pragma unroll
        for (int k = 0; k < 4; ++k) {
            unsigned int u = tile[cq + k][tr];
            h4[k] = (unsigned short)(u >> 16);
            l4[k] = (unsigned short)(u & 0xffff);
        }
        long long tok = (long long)n * T_ + t0 + tr;
        *(uint2*)&xhi[tok * C_ + c0 + cq] = *(uint2*)h4;
        *(uint2*)&xlo[tok * C_ + c0 + cq] = *(uint2*)l4;
    }
}

// ---------------------------------------------- MFMA argmin: 128 tok x 512 codes per block
// grid (256, 4). 4 waves: moff=(w>>1)*64, noff=(w&1)*64. Partial group g = jn*2 + (w&1).
#define BK 64
#define LDA 72   // halfs per row (BK + 8 pad -> 2-way-free banks)
__global__ __launch_bounds__(256)
void k_argmin(const float* __restrict__ out_ro, float* __restrict__ out) {
    extern __shared__ unsigned short sm[];
    unsigned short* As_hi = sm;                    // 128*72
    unsigned short* As_lo = sm + 128 * LDA;
    unsigned short* Bs_hi = sm + 2 * 128 * LDA;
    unsigned short* Bs_lo = sm + 3 * 128 * LDA;
    const unsigned short* xhi = (const unsigned short*)(out_ro + OFF_XD);
    const unsigned short* xlo = xhi + (long long)NTOK * C_;
    const unsigned short* chi = (const unsigned short*)(out_ro + OFF_CSUM);
    const unsigned short* clo = chi + (long long)NCODE * K;
    const float* nrm = out_ro + S_NRM;

    const int tid = threadIdx.x;
    const int it = blockIdx.x;                     // token tile (128)
    const int jn = blockIdx.y;                     // code group (512)
    const int w = tid >> 6, L = tid & 63;
    const int quad = L >> 4, l16 = L & 15;
    const int moff = (w >> 1) * 64, noff = (w & 1) * 64;

    float bd[4][4];
    int   bj[4][4];
    #pragma unroll
    for (int mt = 0; mt < 4; ++mt)
        #pragma unroll
        for (int r = 0; r < 4; ++r) { bd[mt][r] = 3.4e38f; bj[mt][r] = 0; }

    const int arow = it * 128;
    for (int jt = 0; jt < 4; ++jt) {
        const int jbase = jn * 512 + jt * 128;
        f32x4 acc[4][4];
        #pragma unroll
        for (int mt = 0; mt < 4; ++mt)
            #pragma unroll
            for (int nt = 0; nt < 4; ++nt) acc[mt][nt] = (f32x4)(0.0f);

        for (int kc = 0; kc < K; kc += BK) {
            __syncthreads();
            #pragma unroll
            for (int i = 0; i < 4; ++i) {
                int s = tid + 256 * i;
                int r = s >> 3, c = (s & 7) * 8;
                *(uint4*)&As_hi[r * LDA + c] = *(const uint4*)&xhi[(long long)(arow + r) * C_ + kc + c];
                *(uint4*)&As_lo[r * LDA + c] = *(const uint4*)&xlo[(long long)(arow + r) * C_ + kc + c];
                *(uint4*)&Bs_hi[r * LDA + c] = *(const uint4*)&chi[(long long)(jbase + r) * K + kc + c];
                *(uint4*)&Bs_lo[r * LDA + c] = *(const uint4*)&clo[(long long)(jbase + r) * K + kc + c];
            }
            __syncthreads();
            #pragma unroll
            for (int ks = 0; ks < 2; ++ks) {
                bf16x8 ah[4], al[4], bh[4], bl[4];
                #pragma unroll
                for (int mt = 0; mt < 4; ++mt) {
                    int rowa = (moff + mt * 16 + l16) * LDA + ks * 32 + quad * 8;
                    ah[mt] = *(const bf16x8*)&As_hi[rowa];
                    al[mt] = *(const bf16x8*)&As_lo[rowa];
                }
                #pragma unroll
                for (int nt = 0; nt < 4; ++nt) {
                    int rowb = (noff + nt * 16 + l16) * LDA + ks * 32 + quad * 8;
                    bh[nt] = *(const bf16x8*)&Bs_hi[rowb];
                    bl[nt] = *(const bf16x8*)&Bs_lo[rowb];
                }
                #pragma unroll
                for (int mt = 0; mt < 4; ++mt)
                    #pragma unroll
                    for (int nt = 0; nt < 4; ++nt)
                        acc[mt][nt] = __builtin_amdgcn_mfma_f32_16x16x32_bf16(ah[mt], bh[nt], acc[mt][nt], 0, 0, 0);
                #pragma unroll
                for (int mt = 0; mt < 4; ++mt)
                    #pragma unroll
                    for (int nt = 0; nt < 4; ++nt)
                        acc[mt][nt] = __builtin_amdgcn_mfma_f32_16x16x32_bf16(al[mt], bh[nt], acc[mt][nt], 0, 0, 0);
                #pragma unroll
                for (int mt = 0; mt < 4; ++mt)
                    #pragma unroll
                    for (int nt = 0; nt < 4; ++nt)
                        acc[mt][nt] = __builtin_amdgcn_mfma_f32_16x16x32_bf16(ah[mt], bl[nt], acc[mt][nt], 0, 0, 0);
            }
        }
        // epilogue: fold this 128-code tile into running per-token best
        #pragma unroll
        for (int nt = 0; nt < 4; ++nt) {
            int n = jbase + noff + nt * 16 + l16;
            float nv = nrm[n];
            #pragma unroll
            for (int mt = 0; mt < 4; ++mt)
                #pragma unroll
                for (int r = 0; r < 4; ++r) {
                    float d = nv - acc[mt][nt][r];
                    if (d < bd[mt][r]) { bd[mt][r] = d; bj[mt][r] = n; }
                }
        }
    }

    // cross-lane reduce over the 16 lanes of each quad (xor masks 1,2,4,8)
    #pragma unroll
    for (int off = 1; off < 16; off <<= 1) {
        #pragma unroll
        for (int mt = 0; mt < 4; ++mt)
            #pragma unroll
            for (int r = 0; r < 4; ++r) {
                float od = __shfl_xor(bd[mt][r], off, 64);
                int   oj = __shfl_xor(bj[mt][r], off, 64);
                if (od < bd[mt][r] || (od == bd[mt][r] && oj < bj[mt][r])) {
                    bd[mt][r] = od; bj[mt][r] = oj;
                }
            }
    }
    if (l16 == 0) {
        int g = jn * 2 + (w & 1);
        float* pbd = out + S_PBD + (long long)g * NTOK;
        int*   pbj = (int*)(out + S_PBJ) + (long long)g * NTOK;
        #pragma unroll
        for (int mt = 0; mt < 4; ++mt)
            #pragma unroll
            for (int r = 0; r < 4; ++r) {
                int tok = it * 128 + moff + mt * 16 + quad * 4 + r;
                pbd[tok] = bd[mt][r];
                pbj[tok] = bj[mt][r];
            }
    }
}

// ---------------------------------------------- merge 8 partials -> idx
__global__ void k_merge(const float* __restrict__ out_ro, int* __restrict__ idx) {
    int t = blockIdx.x * 256 + threadIdx.x;
    const float* pbd = out_ro + S_PBD;
    const int*   pbj = (const int*)(out_ro + S_PBJ);
    float bd = 3.4e38f; int bj = 0;
    #pragma unroll
    for (int g = 0; g < 8; ++g) {
        float d = pbd[(long long)g * NTOK + t];
        int   j = pbj[(long long)g * NTOK + t];
        if (d < bd || (d == bd && j < bj)) { bd = d; bj = j; }
    }
    idx[t] = bj;
}

// ---------------------------------------------- counting sort
__global__ void k_hist(const int* __restrict__ idx, int* __restrict__ cnt) {
    int t = blockIdx.x * 256 + threadIdx.x;
    atomicAdd(&cnt[idx[t]], 1);
}

__global__ void k_scan(const int* __restrict__ cnt, int* __restrict__ base,
                       int* __restrict__ cursor, const float* __restrict__ code_count,
                       float* __restrict__ out) {
    __shared__ int ps[256];
    __shared__ float hs[256];
    int tid = threadIdx.x;
    int local[8]; int s = 0;
    #pragma unroll
    for (int q = 0; q < 8; ++q) { local[q] = cnt[tid * 8 + q]; s += local[q]; }
    ps[tid] = s; __syncthreads();
    for (int st = 1; st < 256; st <<= 1) {
        int v = (tid >= st) ? ps[tid - st] : 0;
        __syncthreads();
        ps[tid] += v;
        __syncthreads();
    }
    int b = ps[tid] - s;
    float h = 0.0f;
    #pragma unroll
    for (int q = 0; q < 8; ++q) {
        int j = tid * 8 + q;
        base[j] = b; cursor[j] = b; b += local[q];
        float p = (float)local[q] * (1.0f / 32768.0f);
        h += p * logf(p + 1e-7f);
        out[OFF_CCNT + j] = MUF * code_count[j] + OMM * (float)local[q];
    }
    hs[tid] = h; __syncthreads();
    for (int st = 128; st > 0; st >>= 1) {
        if (tid < st) hs[tid] += hs[tid + st];
        __syncthreads();
    }
    if (tid == 0) out[OFF_PERP] = expf(-hs[0]);
}

__global__ void k_place(const int* __restrict__ idx, int* __restrict__ cursor,
                        int* __restrict__ toklist) {
    int t = blockIdx.x * 256 + threadIdx.x;
    int pos = atomicAdd(&cursor[idx[t]], 1);
    toklist[pos] = t;
}

// ---------------------------------------------- code_sum_ema rows (coalesced token-row gather)
__global__ void k_codesum(const float* __restrict__ code_sum,
                          const int* __restrict__ cnt, const int* __restrict__ base,
                          const int* __restrict__ toklist, float* __restrict__ out) {
    int j = blockIdx.x, l = threadIdx.x;      // 2048 x 64
    const unsigned short* xhi = (const unsigned short*)(out + OFF_XD);
    const unsigned short* xlo = xhi + (long long)NTOK * C_;
    float acc[8];
    #pragma unroll
    for (int q = 0; q < 8; ++q) acc[q] = 0.0f;
    int b = base[j], e = b + cnt[j];
    for (int i = b; i < e; ++i) {
        long long tok = toklist[i];
        uint4 hv = *(const uint4*)&xhi[tok * C_ + l * 8];
        uint4 lv = *(const uint4*)&xlo[tok * C_ + l * 8];
        unsigned int hu[4] = {hv.x, hv.y, hv.z, hv.w};
        unsigned int lu[4] = {lv.x, lv.y, lv.z, lv.w};
        #pragma unroll
        for (int q = 0; q < 4; ++q) {
            acc[q * 2 + 0] += bf2f((unsigned short)(hu[q] & 0xffff)) + bf2f((unsigned short)(lu[q] & 0xffff));
            acc[q * 2 + 1] += bf2f((unsigned short)(hu[q] >> 16))    + bf2f((unsigned short)(lu[q] >> 16));
        }
    }
    #pragma unroll
    for (int q = 0; q < 8; ++q) {
        long long o = (long long)j * C_ + l * 8 + q;
        out[OFF_CSUM + o] = MUF * code_sum[o] + OMM * acc[q];
    }
}

// ---------------------------------------------- x_d_out + commit loss (overwrites x_hi/x_lo)
__global__ void k_xd(const float* __restrict__ x, const float* __restrict__ cb,
                     const int* __restrict__ idx, float* __restrict__ out) {
    const int t = blockIdx.x * 256 + threadIdx.x;  // grid (4,4,32)
    const int c0 = blockIdx.y * 128;
    const int n = blockIdx.z;
    const int j = idx[n * T_ + t];
    const float* cr = cb + (long long)j * C_ + c0;
    const long long base = (long long)n * C_ * T_ + t;
    float ls = 0.0f;
    for (int ci = 0; ci < 128; ++ci) {
        float xv = x[base + (long long)(c0 + ci) * T_];
        float dv = cr[ci] - xv;
        out[OFF_XD + base + (long long)(c0 + ci) * T_] = xv + dv;
        ls += dv * dv;
    }
    #pragma unroll
    for (int off = 32; off >= 1; off >>= 1) ls += __shfl_down(ls, off, 64);
    __shared__ float red[4];
    if ((threadIdx.x & 63) == 0) red[threadIdx.x >> 6] = ls;
    __syncthreads();
    if (threadIdx.x == 0) atomicAdd(&out[OFF_LOSS], red[0] + red[1] + red[2] + red[3]);
}

// ---------------------------------------------- codebook update/reset (overwrites CB scratch) + loss scale
__global__ void k_update_cb(const float* __restrict__ x, float* __restrict__ out) {
    int e = blockIdx.x * 256 + threadIdx.x;   // 4096 blocks
    int j = e >> 9, c = e & 511;
    float cema = out[OFF_CCNT + j];
    float se = out[OFF_CSUM + e];
    float val;
    if (cema >= 1.0f) val = se / fmaxf(cema, 1e-10f);
    else val = x[(long long)(j >> 10) * C_ * T_ + (long long)c * T_ + (j & 1023)];
    out[OFF_CB + e] = val;
    if (e == 0) out[OFF_LOSS] *= (1.0f / 16777216.0f);
}

// ---------------------------------------------- launch
extern "C" void kernel_launch(void* const* d_in, const int* in_sizes, int n_in,
                              void* d_out, int out_size, void* d_ws, size_t ws_size,
                              hipStream_t stream) {
    const float* x          = (const float*)d_in[0];
    const float* codebook   = (const float*)d_in[1];
    const float* code_sum   = (const float*)d_in[2];
    const float* code_count = (const float*)d_in[3];
    float* out = (float*)d_out;
    int*   idx     = (int*)(out + S_IDX);
    int*   cnt     = (int*)(out + S_CNT);
    int*   base    = (int*)(out + S_BASE);
    int*   cursor  = (int*)(out + S_CUR);
    int*   toklist = (int*)(out + S_TOK);

    constexpr int SMEM_ARGMIN = 4 * 128 * LDA * 2;   // 73728 B
    static bool attr_set = false;
    hipFuncSetAttribute((const void*)k_argmin,
                        hipFuncAttributeMaxDynamicSharedMemorySize, SMEM_ARGMIN);
    (void)attr_set;

    k_prep_cb  <<<NCODE, 64, 0, stream>>>(codebook, out);
    dim3 gt(16, 8, 32);
    k_transpose<<<gt, 256, 0, stream>>>(x, out);
    dim3 ga(256, 4);
    k_argmin   <<<ga, 256, SMEM_ARGMIN, stream>>>(out, out);
    k_merge    <<<128, 256, 0, stream>>>(out, idx);
    k_hist     <<<128, 256, 0, stream>>>(idx, cnt);
    k_scan     <<<1, 256, 0, stream>>>(cnt, base, cursor, code_count, out);
    k_place    <<<128, 256, 0, stream>>>(idx, cursor, toklist);
    k_codesum  <<<NCODE, 64, 0, stream>>>(code_sum, cnt, base, toklist, out);
    dim3 gx(4, 4, 32);
    k_xd       <<<gx, 256, 0, stream>>>(x, codebook, idx, out);
    k_update_cb<<<4096, 256, 0, stream>>>(x, out);
}